// Round 1
// baseline (72.793 us; speedup 1.0000x reference)
//
#include <hip/hip_runtime.h>
#include <stdint.h>

#define Bb 8
#define Kc 256
#define NHALF 1024
#define Mtot 2048

typedef short bf16x8 __attribute__((ext_vector_type(8)));
typedef float f32x4 __attribute__((ext_vector_type(4)));
typedef unsigned int u32x4 __attribute__((ext_vector_type(4)));

// ---- workspace layout (bytes) ----
#define OFF_ABF  0
#define OFF_SQ   (Bb*Mtot*Kc*2)            // 8388608 : Abf [B][M][K] bf16
#define OFF_VROW (OFF_SQ + Bb*Mtot*4)      // sq [B][M] f32
#define OFF_C    (OFF_VROW + Bb*Kc*4)      // vrow [B][K] f32
#define OFF_TOT  (OFF_C + 32)              // c[5] f32 (padded), then total (double)

__device__ __forceinline__ unsigned short f2bf(float v) {
  unsigned u = __float_as_uint(v);
  unsigned r = u + 0x7FFFu + ((u >> 16) & 1u);   // RNE
  return (unsigned short)(r >> 16);
}
__device__ __forceinline__ float bf2f(unsigned short h) {
  return __uint_as_float(((unsigned)h) << 16);
}

// K1: transpose f32 [b][k][m] -> bf16 Abf [b][m][k], accumulate sq[b][m] = sum_k xhat^2
__global__ __launch_bounds__(256) void k_prep(const float* __restrict__ s,
                                              const float* __restrict__ t,
                                              unsigned short* __restrict__ Abf,
                                              float* __restrict__ sq) {
  const int bi = blockIdx.x;
  const int b = bi >> 5;
  const int mblk = (bi >> 2) & 7;
  const int kq = bi & 3;
  const int m = mblk * 256 + threadIdx.x;
  const float* __restrict__ p = (m < NHALF) ? (s + (size_t)b * Kc * NHALF + m)
                                            : (t + (size_t)b * Kc * NHALF + (m - NHALF));
  unsigned short* __restrict__ dst = Abf + ((size_t)b * Mtot + m) * Kc;
  float sqv = 0.f;
  const int kend = kq * 64 + 64;
  for (int k0 = kq * 64; k0 < kend; k0 += 8) {
    unsigned short h[8];
#pragma unroll
    for (int j = 0; j < 8; ++j) {
      float v = p[(size_t)(k0 + j) * NHALF];
      h[j] = f2bf(v);
      float hv = bf2f(h[j]);
      sqv = fmaf(hv, hv, sqv);
    }
    u32x4 v4;
    v4.x = (unsigned)h[0] | ((unsigned)h[1] << 16);
    v4.y = (unsigned)h[2] | ((unsigned)h[3] << 16);
    v4.z = (unsigned)h[4] | ((unsigned)h[5] << 16);
    v4.w = (unsigned)h[6] | ((unsigned)h[7] << 16);
    *(u32x4*)(dst + k0) = v4;
  }
  atomicAdd(&sq[b * Mtot + m], sqv);
}

// K1b: vrow[b][k] = sum_m X[k][m] (f32 originals; bandwidth tolerance is loose)
__global__ __launch_bounds__(256) void k_rowsum(const float* __restrict__ s,
                                                const float* __restrict__ t,
                                                float* __restrict__ vrow) {
  const int b = blockIdx.x >> 8;
  const int k = blockIdx.x & 255;
  const float* __restrict__ ps = s + ((size_t)(b * Kc + k)) * NHALF;
  const float* __restrict__ pt = t + ((size_t)(b * Kc + k)) * NHALF;
  float acc = 0.f;
  for (int i = threadIdx.x; i < NHALF; i += 256) acc += ps[i] + pt[i];
#pragma unroll
  for (int o = 32; o > 0; o >>= 1) acc += __shfl_down(acc, o);
  __shared__ float red[4];
  if ((threadIdx.x & 63) == 0) red[threadIdx.x >> 6] = acc;
  __syncthreads();
  if (threadIdx.x == 0) vrow[b * Kc + k] = red[0] + red[1] + red[2] + red[3];
}

// K2: bandwidth via closed form; write 5 coefficients; zero the f64 accumulator
__global__ __launch_bounds__(256) void k_bw(const float* __restrict__ sq,
                                            const float* __restrict__ vrow,
                                            float* __restrict__ cc,
                                            double* __restrict__ total) {
  double s1 = 0.0, v2 = 0.0;
  for (int i = threadIdx.x; i < Bb * Mtot; i += 256) s1 += (double)sq[i];
  for (int i = threadIdx.x; i < Bb * Kc; i += 256) { double x = (double)vrow[i]; v2 += x * x; }
#pragma unroll
  for (int o = 32; o > 0; o >>= 1) { s1 += __shfl_down(s1, o); v2 += __shfl_down(v2, o); }
  __shared__ double rs[4], rv[4];
  if ((threadIdx.x & 63) == 0) { rs[threadIdx.x >> 6] = s1; rv[threadIdx.x >> 6] = v2; }
  __syncthreads();
  if (threadIdx.x == 0) {
    double S1 = rs[0] + rs[1] + rs[2] + rs[3];
    double V2 = rv[0] + rv[1] + rv[2] + rv[3];
    double sumL2 = 2.0 * (double)Mtot * S1 - 2.0 * V2;
    double bw = sumL2 / ((double)Mtot * (double)(Mtot - 1)) / 4.0;  // / KERNEL_MUL^(5//2)
#pragma unroll
    for (int i = 0; i < 5; ++i) cc[i] = (float)(1.0 / (bw * (double)(1 << i)));
    *total = 0.0;
  }
}

// K3: fused gram(X^T X) + L2 + 5-kernel exp sum + signed reduce.
// Triangular tile grid (mi<=mj), off-diagonal tiles weighted x2 (matrix symmetric).
__global__ __launch_bounds__(256) void k_mmd(const unsigned short* __restrict__ Abf,
                                             const float* __restrict__ sq,
                                             const float* __restrict__ cc,
                                             double* __restrict__ total) {
  __shared__ unsigned short As[128 * 32];
  __shared__ unsigned short Bs[128 * 32];
  __shared__ float red[4];

  const int b = blockIdx.y;
  int rem = blockIdx.x;                 // 0..135 triangular index
  int mi = 0;
  while (rem >= 16 - mi) { rem -= 16 - mi; ++mi; }
  const int mj = mi + rem;

  const int tid = threadIdx.x;
  const int lane = tid & 63;
  const int wid = tid >> 6;             // 4 waves, 2x2 wave grid, 64x64 each
  const int wr = wid >> 1, wc = wid & 1;
  const int l15 = lane & 15;
  const int k8 = lane >> 4;
  const int r0 = tid >> 2;              // staging row (pass 0)
  const int slot = tid & 3;             // 16B slot within 64B row

  const size_t boff = (size_t)b * Mtot * Kc;

  f32x4 acc[4][4];
  const f32x4 zero = {0.f, 0.f, 0.f, 0.f};
#pragma unroll
  for (int i = 0; i < 4; ++i)
#pragma unroll
    for (int j = 0; j < 4; ++j) acc[i][j] = zero;

  for (int kt = 0; kt < 8; ++kt) {
    const int kbase = kt * 32;
    // stage 2 tiles of [128 rows][32 k] bf16, LDS linear dest, XOR-swizzled SOURCE
    // (slot' = slot ^ ((row>>1)&3) spreads the 64B rows across the 128B bank cycle)
#pragma unroll
    for (int pass = 0; pass < 2; ++pass) {
      const int r = r0 + pass * 64;
      const int sg = slot ^ ((r >> 1) & 3);
      const unsigned short* gA = Abf + boff + (size_t)(mi * 128 + r) * Kc + kbase + sg * 8;
      const unsigned short* gB = Abf + boff + (size_t)(mj * 128 + r) * Kc + kbase + sg * 8;
      char* lA = (char*)As + pass * 4096 + tid * 16;
      char* lB = (char*)Bs + pass * 4096 + tid * 16;
      __builtin_amdgcn_global_load_lds(
          (const __attribute__((address_space(1))) unsigned int*)(uintptr_t)gA,
          (__attribute__((address_space(3))) unsigned int*)(uintptr_t)lA, 16, 0, 0);
      __builtin_amdgcn_global_load_lds(
          (const __attribute__((address_space(1))) unsigned int*)(uintptr_t)gB,
          (__attribute__((address_space(3))) unsigned int*)(uintptr_t)lB, 16, 0, 0);
    }
    __syncthreads();

    bf16x8 af[4], bfr[4];
#pragma unroll
    for (int si = 0; si < 4; ++si) {
      const int ra = wr * 64 + si * 16 + l15;
      af[si] = *(const bf16x8*)((const char*)As + ra * 64 + ((k8 ^ ((ra >> 1) & 3)) * 16));
      const int rb = wc * 64 + si * 16 + l15;
      bfr[si] = *(const bf16x8*)((const char*)Bs + rb * 64 + ((k8 ^ ((rb >> 1) & 3)) * 16));
    }
#pragma unroll
    for (int si = 0; si < 4; ++si)
#pragma unroll
      for (int sj = 0; sj < 4; ++sj)
        acc[si][sj] = __builtin_amdgcn_mfma_f32_16x16x32_bf16(af[si], bfr[sj], acc[si][sj], 0, 0, 0);
    __syncthreads();
  }

  // epilogue: L2 = sq[m]+sq[n]-2g ; ksum = sum_i exp(-L2 * c[i])
  const float c0 = cc[0], c1 = cc[1], c2 = cc[2], c3 = cc[3], c4 = cc[4];
  const float* sqb = sq + b * Mtot;
  const int mbase = mi * 128 + wr * 64;
  const int nbase = mj * 128 + wc * 64;
  float sqn[4];
#pragma unroll
  for (int sj = 0; sj < 4; ++sj) sqn[sj] = sqb[nbase + sj * 16 + l15];
  float lsum = 0.f;
#pragma unroll
  for (int si = 0; si < 4; ++si) {
#pragma unroll
    for (int rg = 0; rg < 4; ++rg) {
      const int m = mbase + si * 16 + (lane >> 4) * 4 + rg;   // C/D: row=(l>>4)*4+reg
      const float sqm = sqb[m];
#pragma unroll
      for (int sj = 0; sj < 4; ++sj) {
        const float g = acc[si][sj][rg];
        const float nl2 = fmaf(2.f, g, -sqm) - sqn[sj];       // -L2
        lsum += __expf(nl2 * c0) + __expf(nl2 * c1) + __expf(nl2 * c2)
              + __expf(nl2 * c3) + __expf(nl2 * c4);
      }
    }
  }
  // sign: +1 same quadrant (XX,YY), -1 cross (XY,YX); weight 2 for off-diag tiles
  const float wsgn = ((mi == mj) ? 1.f : 2.f) * (((mi < 8) == (mj < 8)) ? 1.f : -1.f);
  lsum *= wsgn;
#pragma unroll
  for (int o = 32; o > 0; o >>= 1) lsum += __shfl_down(lsum, o);
  if (lane == 0) red[wid] = lsum;
  __syncthreads();
  if (tid == 0) {
    double bs = (double)red[0] + (double)red[1] + (double)red[2] + (double)red[3];
    atomicAdd(total, bs);
  }
}

__global__ void k_final(const double* __restrict__ total, float* __restrict__ out) {
  out[0] = (float)(*total / ((double)Bb * (double)NHALF * (double)NHALF));
}

extern "C" void kernel_launch(void* const* d_in, const int* in_sizes, int n_in,
                              void* d_out, int out_size, void* d_ws, size_t ws_size,
                              hipStream_t stream) {
  const float* src = (const float*)d_in[0];
  const float* tgt = (const float*)d_in[1];
  char* ws = (char*)d_ws;
  unsigned short* Abf = (unsigned short*)(ws + OFF_ABF);
  float* sq   = (float*)(ws + OFF_SQ);
  float* vrow = (float*)(ws + OFF_VROW);
  float* cc   = (float*)(ws + OFF_C);
  double* total = (double*)(ws + OFF_TOT);
  float* out = (float*)d_out;

  hipMemsetAsync(sq, 0, Bb * Mtot * sizeof(float), stream);
  k_prep<<<256, 256, 0, stream>>>(src, tgt, Abf, sq);
  k_rowsum<<<2048, 256, 0, stream>>>(src, tgt, vrow);
  k_bw<<<1, 256, 0, stream>>>(sq, vrow, cc, total);
  k_mmd<<<dim3(136, Bb), 256, 0, stream>>>(Abf, sq, cc, total);
  k_final<<<1, 1, 0, stream>>>(total, out);
}